// Round 18
// baseline (100.100 us; speedup 1.0000x reference)
//
#include <hip/hip_runtime.h>
#include <math.h>

// DynamicRouting: C=1024, K=64, H=512.
// Round-18 = round-17 split (proj -> xhat in ws; route reads xhat) with the
// route staging index FIXED: 4096 chunks / 64 rows = 64 chunks/row, so
// row = flat>>6, col = (flat&63)<<3 (r17 had >>5/&31 -> OOB LDS + garbage).
// Purpose unchanged: per-dispatch rocprof ablates projection vs routing cost
// (fused r12/r15/r16 pinned at 81-89us regardless of barrier structure).
// Verified pieces: staging swizzle + Wp B-frag order + MFMA layout (r12-r16);
// r7 bdot pattern; r15 alpha ordering. Fallback: r16 fused kernel.

#define KC 64
#define HD 512
#define NT 512

typedef _Float16 half8  __attribute__((ext_vector_type(8)));
typedef _Float16 half4v __attribute__((ext_vector_type(4)));
typedef float    f32x4  __attribute__((ext_vector_type(4)));

// ---- W (fp32 [g][h]) -> fp16 in B-fragment order (verified r12) ----
__launch_bounds__(256)
__global__ void cast_w_kernel(const float* __restrict__ W, _Float16* __restrict__ Wp) {
    int u    = blockIdx.x * 256 + threadIdx.x;    // 0..32767
    int lane = u & 63;
    int j    = (u >> 6) & 3;
    int ks   = (u >> 8) & 1;
    int hs   = (u >> 9) & 7;
    int wv   = (u >> 12) & 7;
    int g  = wv * 64 + j * 16 + (lane & 15);
    int h0 = hs * 64 + ks * 32 + (lane >> 4) * 8;
    const float4* src = reinterpret_cast<const float4*>(W + (size_t)g * HD + h0);
    float4 a = src[0], b = src[1];
    half8 h = { (_Float16)a.x, (_Float16)a.y, (_Float16)a.z, (_Float16)a.w,
                (_Float16)b.x, (_Float16)b.y, (_Float16)b.z, (_Float16)b.w };
    *reinterpret_cast<half8*>(Wp + (size_t)u * 8) = h;
}

// ---- kernel A: xhat[c] = Enc_c @ W^T (r16 projection, routing removed) ----
__launch_bounds__(NT, 2)
__global__ void proj_kernel(const float* __restrict__ enc,
                            const _Float16* __restrict__ Wp,
                            _Float16* __restrict__ xhat) {
    __shared__ _Float16 slab[8][8][64][8];      // 64 KB [hs][plane][row][e]

    const int tid  = threadIdx.x;
    const int lane = tid & 63;
    const int wave = tid >> 6;
    const int l15  = lane & 15, l4 = lane >> 4;
    const int c    = blockIdx.x;
    const float* ebase = enc + (size_t)c * (KC * HD);
    const _Float16* wbase = Wp + ((size_t)wave << 15) + (lane << 3);

    // staging geometry (verified r12)
    const int r0   = tid >> 4;
    const int c40  = (tid & 15) << 2;
    const int ks_w = c40 >> 5;
    const int l4g  = (c40 >> 3) & 3;
    const int e0w  = c40 & 7;
    const int prow = (l4g * 16 + (r0 & 15)) ^ (l4g << 1);
    const int p0   = (r0 >> 4) * 2 + ks_w;
    const int p1   = p0 + 4;
    const int plane_r = lane ^ ((lane >> 4) << 1);

    half8 bf[2][8];
    auto bload = [&](int hs) {
        #pragma unroll
        for (int q = 0; q < 8; ++q)
            bf[hs & 1][q] = *reinterpret_cast<const half8*>(wbase + hs * 4096 + q * 512);
    };

    // stage whole capsule in one burst (deep MLP)
    float4 ev[8][2];
    #pragma unroll
    for (int hs = 0; hs < 8; ++hs) {
        ev[hs][0] = *reinterpret_cast<const float4*>(ebase + (size_t)r0 * HD + hs * 64 + c40);
        ev[hs][1] = *reinterpret_cast<const float4*>(ebase + (size_t)(r0 + 32) * HD + hs * 64 + c40);
    }
    bload(0);
    #pragma unroll
    for (int hs = 0; hs < 8; ++hs) {
        float4 v0 = ev[hs][0], v1 = ev[hs][1];
        half4v h0 = { (_Float16)v0.x, (_Float16)v0.y, (_Float16)v0.z, (_Float16)v0.w };
        half4v h1 = { (_Float16)v1.x, (_Float16)v1.y, (_Float16)v1.z, (_Float16)v1.w };
        *reinterpret_cast<half4v*>(&slab[hs][p0][prow][e0w]) = h0;
        *reinterpret_cast<half4v*>(&slab[hs][p1][prow][e0w]) = h1;
    }

    f32x4 acc[16];
    #pragma unroll
    for (int i = 0; i < 16; ++i) acc[i] = (f32x4){0.f, 0.f, 0.f, 0.f};

    __syncthreads();

    #pragma unroll
    for (int hs = 0; hs < 8; ++hs) {
        if (hs < 7) bload(hs + 1);
        #pragma unroll
        for (int ks = 0; ks < 2; ++ks) {
            half8 af[4];
            #pragma unroll
            for (int i = 0; i < 4; ++i)
                af[i] = *reinterpret_cast<const half8*>(&slab[hs][i * 2 + ks][plane_r][0]);
            #pragma unroll
            for (int i = 0; i < 4; ++i)
                #pragma unroll
                for (int j = 0; j < 4; ++j)
                    acc[i * 4 + j] = __builtin_amdgcn_mfma_f32_16x16x32_f16(
                        af[i], bf[hs & 1][ks * 4 + j], acc[i * 4 + j], 0, 0, 0);
        }
    }

    // epilogue: acc -> xhat[c][k][g] fp16
    _Float16* xrow = xhat + (size_t)c * (KC * HD);
    #pragma unroll
    for (int i = 0; i < 4; ++i) {
        #pragma unroll
        for (int j = 0; j < 4; ++j) {
            f32x4 v = acc[i * 4 + j];
            const int g  = wave * 64 + j * 16 + l15;
            const int kb = i * 16 + l4 * 4;
            #pragma unroll
            for (int r = 0; r < 4; ++r)
                xrow[(size_t)(kb + r) * HD + g] = (_Float16)v[r];
        }
    }
}

// ---- kernel B: routing from xhat (LDS-staged, r7/r15-verified patterns) ----
__launch_bounds__(NT, 2)
__global__ void route_kernel(const _Float16* __restrict__ xhat,
                             float* __restrict__ out) {
    __shared__ _Float16 xh[KC][520];            // ~66.5 KB (pad 520)
    __shared__ float chatL[HD];
    __shared__ float dL[KC];
    __shared__ float bdotL[KC];                 // alpha-folded dots
    __shared__ float red[8];

    const int tid  = threadIdx.x;
    const int lane = tid & 63;
    const int wave = tid >> 6;
    const int c    = blockIdx.x;
    const _Float16* xsrc = xhat + (size_t)c * (KC * HD);

    // stage xhat_c: 4096 16B chunks, 64 chunks per row (FIXED r17 bug)
    #pragma unroll
    for (int q = 0; q < 8; ++q) {
        int flat = tid + q * 512;               // 0..4095
        int row  = flat >> 6;                   // 64 chunks per 512-half row
        int col  = (flat & 63) << 3;            // half offset 0..504
        half8 v = *reinterpret_cast<const half8*>(xsrc + (size_t)row * HD + col);
        *reinterpret_cast<half8*>(&xh[row][col]) = v;
    }
    __syncthreads();

    float breg = 0.0f;                          // b[k=lane], wave-redundant
    float alpha = 0.0f;

    #pragma unroll
    for (int it = 0; it < 3; ++it) {
        // ---- d ----
        if (it > 0) {
            breg += bdotL[lane];                // alpha folded at bdot time
            float m = breg;
            #pragma unroll
            for (int off = 32; off; off >>= 1) m = fmaxf(m, __shfl_xor(m, off));
            float e = expf(breg - m);
            float se = e;
            #pragma unroll
            for (int off = 32; off; off >>= 1) se += __shfl_xor(se, off);
            if (wave == 0) dL[lane] = e / se;
            __syncthreads();
        }

        // ---- chat[h=tid] = sum_k d_k xh[k][h] ; n2 partials ----
        {
            float cs = 0.f;
            if (it == 0) {
                #pragma unroll 8
                for (int k = 0; k < KC; ++k) cs += (float)xh[k][tid];
                cs *= (1.0f / 64.0f);
            } else {
                #pragma unroll 8
                for (int k = 0; k < KC; ++k) cs += dL[k] * (float)xh[k][tid];
            }
            chatL[tid] = cs;
            float p = cs * cs;
            #pragma unroll
            for (int off = 32; off; off >>= 1) p += __shfl_xor(p, off);
            if (lane == 0) red[wave] = p;
        }
        __syncthreads();
        {
            float n2 = red[0] + red[1] + red[2] + red[3]
                     + red[4] + red[5] + red[6] + red[7];
            alpha = sqrtf(n2) / (1.0f + n2);
        }

        if (it < 2) {
            // ---- bdotL[k] = alpha * dot(xh_k, chat), wave-per-8k (r7 pattern) ----
            float4 cA = *reinterpret_cast<const float4*>(&chatL[lane * 8]);
            float4 cB = *reinterpret_cast<const float4*>(&chatL[lane * 8 + 4]);
            #pragma unroll
            for (int kk = 0; kk < 8; ++kk) {
                int k = wave * 8 + kk;
                half8 x = *reinterpret_cast<const half8*>(&xh[k][lane * 8]);
                float p = (float)x[0] * cA.x + (float)x[1] * cA.y
                        + (float)x[2] * cA.z + (float)x[3] * cA.w
                        + (float)x[4] * cB.x + (float)x[5] * cB.y
                        + (float)x[6] * cB.z + (float)x[7] * cB.w;
                #pragma unroll
                for (int off = 32; off; off >>= 1) p += __shfl_xor(p, off);
                if (lane == 0) bdotL[k] = alpha * p;
            }
            __syncthreads();
        } else {
            out[(size_t)c * HD + tid] = alpha * chatL[tid];
        }
    }
}

// ---- fallback: r16 fused kernel (verified, 88.6us) ----
__launch_bounds__(NT, 2)
__global__ void fused_kernel(const float* __restrict__ enc,
                             const _Float16* __restrict__ Wp,
                             float* __restrict__ out) {
    __shared__ _Float16 slab[8][8][64][8];
    __shared__ float chatL[HD];
    __shared__ float bpart[2][8][KC];
    __shared__ float redp[2][8];

    const int tid  = threadIdx.x;
    const int lane = tid & 63;
    const int wave = tid >> 6;
    const int l15  = lane & 15, l4 = lane >> 4;
    const int c    = blockIdx.x;
    const float* ebase = enc + (size_t)c * (KC * HD);
    const _Float16* wbase = Wp + ((size_t)wave << 15) + (lane << 3);

    const int r0   = tid >> 4;
    const int c40  = (tid & 15) << 2;
    const int ks_w = c40 >> 5;
    const int l4g  = (c40 >> 3) & 3;
    const int e0w  = c40 & 7;
    const int prow = (l4g * 16 + (r0 & 15)) ^ (l4g << 1);
    const int p0   = (r0 >> 4) * 2 + ks_w;
    const int p1   = p0 + 4;
    const int plane_r = lane ^ ((lane >> 4) << 1);

    half8 bf[2][8];
    auto bload = [&](int hs) {
        #pragma unroll
        for (int q = 0; q < 8; ++q)
            bf[hs & 1][q] = *reinterpret_cast<const half8*>(wbase + hs * 4096 + q * 512);
    };

    float4 ev[8][2];
    #pragma unroll
    for (int hs = 0; hs < 8; ++hs) {
        ev[hs][0] = *reinterpret_cast<const float4*>(ebase + (size_t)r0 * HD + hs * 64 + c40);
        ev[hs][1] = *reinterpret_cast<const float4*>(ebase + (size_t)(r0 + 32) * HD + hs * 64 + c40);
    }
    bload(0);
    #pragma unroll
    for (int hs = 0; hs < 8; ++hs) {
        float4 v0 = ev[hs][0], v1 = ev[hs][1];
        half4v h0 = { (_Float16)v0.x, (_Float16)v0.y, (_Float16)v0.z, (_Float16)v0.w };
        half4v h1 = { (_Float16)v1.x, (_Float16)v1.y, (_Float16)v1.z, (_Float16)v1.w };
        *reinterpret_cast<half4v*>(&slab[hs][p0][prow][e0w]) = h0;
        *reinterpret_cast<half4v*>(&slab[hs][p1][prow][e0w]) = h1;
    }

    f32x4 acc[16];
    #pragma unroll
    for (int i = 0; i < 16; ++i) acc[i] = (f32x4){0.f, 0.f, 0.f, 0.f};

    __syncthreads();

    #pragma unroll
    for (int hs = 0; hs < 8; ++hs) {
        if (hs < 7) bload(hs + 1);
        #pragma unroll
        for (int ks = 0; ks < 2; ++ks) {
            half8 af[4];
            #pragma unroll
            for (int i = 0; i < 4; ++i)
                af[i] = *reinterpret_cast<const half8*>(&slab[hs][i * 2 + ks][plane_r][0]);
            #pragma unroll
            for (int i = 0; i < 4; ++i)
                #pragma unroll
                for (int j = 0; j < 4; ++j)
                    acc[i * 4 + j] = __builtin_amdgcn_mfma_f32_16x16x32_f16(
                        af[i], bf[hs & 1][ks * 4 + j], acc[i * 4 + j], 0, 0, 0);
        }
    }

    float breg = 0.0f;
    float chv[4];
    {
        #pragma unroll
        for (int j = 0; j < 4; ++j) chv[j] = 0.f;
        #pragma unroll
        for (int i = 0; i < 4; ++i)
            #pragma unroll
            for (int r = 0; r < 4; ++r) {
                #pragma unroll
                for (int j = 0; j < 4; ++j)
                    chv[j] += (1.0f / 64.0f) * acc[i * 4 + j][r];
            }
        #pragma unroll
        for (int j = 0; j < 4; ++j) {
            chv[j] += __shfl_xor(chv[j], 16);
            chv[j] += __shfl_xor(chv[j], 32);
        }
        float p = chv[0] * chv[0] + chv[1] * chv[1] + chv[2] * chv[2] + chv[3] * chv[3];
        #pragma unroll
        for (int off = 1; off <= 8; off <<= 1) p += __shfl_xor(p, off);
        if (lane == 0) redp[0][wave] = p;
        #pragma unroll
        for (int i = 0; i < 4; ++i)
            #pragma unroll
            for (int r = 0; r < 4; ++r) {
                float s = acc[i * 4 + 0][r] * chv[0] + acc[i * 4 + 1][r] * chv[1]
                        + acc[i * 4 + 2][r] * chv[2] + acc[i * 4 + 3][r] * chv[3];
                #pragma unroll
                for (int off = 1; off <= 8; off <<= 1) s += __shfl_xor(s, off);
                if (l15 == 0) bpart[0][wave][i * 16 + l4 * 4 + r] = s;
            }
        __syncthreads();
    }
    #pragma unroll
    for (int it = 1; it < 3; ++it) {
        const int rp = (it - 1) & 1, wp = it & 1;
        float n2 = 0.f;
        #pragma unroll
        for (int w = 0; w < 8; ++w) n2 += redp[rp][w];
        float alpha = sqrtf(n2) / (1.0f + n2);
        float dot = 0.f;
        #pragma unroll
        for (int w = 0; w < 8; ++w) dot += bpart[rp][w][lane];
        breg += alpha * dot;
        float m = breg;
        #pragma unroll
        for (int off = 32; off; off >>= 1) m = fmaxf(m, __shfl_xor(m, off));
        float e = expf(breg - m);
        float se = e;
        #pragma unroll
        for (int off = 32; off; off >>= 1) se += __shfl_xor(se, off);
        float dl = e / se;
        #pragma unroll
        for (int j = 0; j < 4; ++j) chv[j] = 0.f;
        #pragma unroll
        for (int i = 0; i < 4; ++i)
            #pragma unroll
            for (int r = 0; r < 4; ++r) {
                float dk = __shfl(dl, i * 16 + l4 * 4 + r);
                #pragma unroll
                for (int j = 0; j < 4; ++j)
                    chv[j] += dk * acc[i * 4 + j][r];
            }
        #pragma unroll
        for (int j = 0; j < 4; ++j) {
            chv[j] += __shfl_xor(chv[j], 16);
            chv[j] += __shfl_xor(chv[j], 32);
        }
        float p = chv[0] * chv[0] + chv[1] * chv[1] + chv[2] * chv[2] + chv[3] * chv[3];
        #pragma unroll
        for (int off = 1; off <= 8; off <<= 1) p += __shfl_xor(p, off);
        if (lane == 0) redp[wp][wave] = p;

        if (it < 2) {
            #pragma unroll
            for (int i = 0; i < 4; ++i)
                #pragma unroll
                for (int r = 0; r < 4; ++r) {
                    float s = acc[i * 4 + 0][r] * chv[0] + acc[i * 4 + 1][r] * chv[1]
                            + acc[i * 4 + 2][r] * chv[2] + acc[i * 4 + 3][r] * chv[3];
                    #pragma unroll
                    for (int off = 1; off <= 8; off <<= 1) s += __shfl_xor(s, off);
                    if (l15 == 0) bpart[wp][wave][i * 16 + l4 * 4 + r] = s;
                }
            __syncthreads();
        } else {
            if (l4 == 0) {
                #pragma unroll
                for (int j = 0; j < 4; ++j)
                    chatL[wave * 64 + j * 16 + l15] = chv[j];
            }
            __syncthreads();
            float n2f = 0.f;
            #pragma unroll
            for (int w = 0; w < 8; ++w) n2f += redp[wp][w];
            float alphaf = sqrtf(n2f) / (1.0f + n2f);
            out[(size_t)c * HD + tid] = alphaf * chatL[tid];
        }
    }
}

extern "C" void kernel_launch(void* const* d_in, const int* in_sizes, int n_in,
                              void* d_out, int out_size, void* d_ws, size_t ws_size,
                              hipStream_t stream) {
    const float* enc = (const float*)d_in[0];   // [1024, 64, 512] fp32
    const float* W   = (const float*)d_in[1];   // [512, 512] fp32
    float* out       = (float*)d_out;           // [1024, 512] fp32
    _Float16* Wp     = (_Float16*)d_ws;         // 512 KB, B-fragment order
    (void)in_sizes; (void)n_in; (void)out_size;

    const size_t wp_bytes   = (size_t)512 * 1024;
    const size_t xhat_bytes = (size_t)1024 * KC * HD * sizeof(_Float16);  // 64 MB

    cast_w_kernel<<<128, 256, 0, stream>>>(W, Wp);
    if (ws_size >= wp_bytes + xhat_bytes) {
        _Float16* xhat = (_Float16*)((char*)d_ws + wp_bytes);
        proj_kernel<<<1024, NT, 0, stream>>>(enc, Wp, xhat);
        route_kernel<<<1024, NT, 0, stream>>>(xhat, out);
    } else {
        fused_kernel<<<1024, NT, 0, stream>>>(enc, Wp, out);
    }
}